// Round 9
// baseline (259.522 us; speedup 1.0000x reference)
//
#include <hip/hip_runtime.h>

#define N_NODES 100000
#define N_EDGES 1600000
#define D 64

#define BSHIFT 7                                   // 128 nodes per bucket
#define BNODES (1 << BSHIFT)                       // 128
#define NB ((N_NODES + BNODES - 1) / BNODES)       // 782 buckets
#define NPAD (NB * BNODES)                         // 100096 (padded node count)
#define PB 256                                     // partition blocks
#define TILE ((N_EDGES + PB - 1) / PB)             // 6250 edges per block (exact)
#define CAP 2432                                   // slack per bucket (mean 2046 + 8.5 sigma)
#define MAXB 4096
#define CAST_BLKS 512                              // cast blocks inside `front`
#define QBLKS ((N_NODES * D / 4 + 1023) / 1024)    // 1563 quant blocks (1024 thr)
#define NT (N_NODES / 16)                          // 6250 node-tiles
#define SGRID 1024                                 // persistent sage blocks (4/CU)
#define HPARTS NT                                  // per-tile h-absmax partials

typedef __attribute__((ext_vector_type(8))) short short8;   // 8 bf16 (4 VGPRs)
typedef __attribute__((ext_vector_type(4))) float float4v;  // MFMA acc
typedef __attribute__((ext_vector_type(2))) unsigned uint2v; // clang vector (nt ok)
typedef __attribute__((ext_vector_type(4))) unsigned uint4v; // clang vector (nt ok)

// round-to-nearest-even fp32 -> bf16 bits (scalar path)
__device__ __forceinline__ unsigned short f2bf(float f) {
    unsigned u = __float_as_uint(f);
    u = (u + 0x7fffu + ((u >> 16) & 1u)) >> 16;
    return (unsigned short)u;
}
// HW packed conversion: dst = [bf16(a) | bf16(b)<<16] in ONE VALU op
__device__ __forceinline__ unsigned cvtpk(float a, float b) {
    unsigned r;
    asm("v_cvt_pk_bf16_f32 %0, %1, %2" : "=v"(r) : "v"(a), "v"(b));
    return r;
}

__device__ __forceinline__ float4 bf16x4_to_f4(uint2 v) {
    float4 r;
    r.x = __uint_as_float(v.x << 16);
    r.y = __uint_as_float(v.x & 0xffff0000u);
    r.z = __uint_as_float(v.y << 16);
    r.w = __uint_as_float(v.y & 0xffff0000u);
    return r;
}

// ---------------------------------------------------------------------------
// FRONT: blocks [0,CAST_BLKS) = cast x->bf16 + partial absmax (grid-stride);
//        blocks [CAST_BLKS, CAST_BLKS+PB) = fused edge partition with
//        LDS-staged coalesced output (round-15 win: slot-ordered drain).
// ---------------------------------------------------------------------------
__global__ __launch_bounds__(1024) void front(const float* __restrict__ x,
                                              unsigned short* __restrict__ xb,
                                              float* __restrict__ partial,
                                              const int* __restrict__ src,
                                              const int* __restrict__ dst,
                                              int* __restrict__ gcnt,
                                              int* __restrict__ part) {
    __shared__ float red[16];
    __shared__ int hist[NB];      // counts -> lbase
    __shared__ int lcur[NB];      // LDS scatter cursors
    __shared__ int gbase[NB];     // per-bucket global base
    __shared__ int ebuf[TILE];    // staged packed edges
    __shared__ int gtgt[TILE];    // per-slot global target (phase-2 scratch)

    int tid = threadIdx.x;

    if (blockIdx.x < CAST_BLKS) {
        float m = 0.0f;
        int stride = CAST_BLKS * 1024;
        for (int i = blockIdx.x * 1024 + tid; i < N_NODES * D / 4; i += stride) {
            float4 v = ((const float4*)x)[i];
            ushort4 o;
            o.x = f2bf(v.x); o.y = f2bf(v.y); o.z = f2bf(v.z); o.w = f2bf(v.w);
            ((ushort4*)xb)[i] = o;
            m = fmaxf(m, fmaxf(fmaxf(fabsf(v.x), fabsf(v.y)), fmaxf(fabsf(v.z), fabsf(v.w))));
        }
        for (int off = 32; off >= 1; off >>= 1) m = fmaxf(m, __shfl_xor(m, off, 64));
        if ((tid & 63) == 0) red[tid >> 6] = m;
        __syncthreads();
        if (tid == 0) {
            float mm = 0.0f;
#pragma unroll
            for (int w = 0; w < 16; ++w) mm = fmaxf(mm, red[w]);
            partial[blockIdx.x] = mm;
        }
        return;
    }

    // ---- partition: count -> reserve -> LDS scatter -> coalesced drain ----
    int bid = blockIdx.x - CAST_BLKS;
    for (int i = tid; i < NB; i += 1024) hist[i] = 0;
    __syncthreads();

    int lo = bid * TILE;                  // 256*6250 == N_EDGES, no tail

    unsigned pk[7];
    int bk[7];
#pragma unroll
    for (int k = 0; k < 7; ++k) {
        int e = lo + tid + k * 1024;
        if (tid + k * 1024 < TILE) {
            int dd = dst[e];
            int ss = src[e];
            int b = dd >> BSHIFT;
            pk[k] = ((unsigned)ss << BSHIFT) | (unsigned)(dd & (BNODES - 1));
            bk[k] = b;
            atomicAdd(&hist[b], 1);
        } else {
            bk[k] = -1;
        }
    }
    __syncthreads();

    // phase 2: global range reservation + block-local exclusive scan
    int h = (tid < NB) ? hist[tid] : 0;
    if (tid < NB)
        gbase[tid] = tid * CAP + (h ? atomicAdd(&gcnt[tid], h) : 0);
    int val = h;
    gtgt[tid] = val;                      // scratch [0..1023]
    __syncthreads();
    for (int off = 1; off < 1024; off <<= 1) {
        int u = (tid >= off) ? gtgt[tid - off] : 0;
        __syncthreads();
        val += u;
        gtgt[tid] = val;
        __syncthreads();
    }
    if (tid < NB) {
        hist[tid] = val - h;              // lbase
        lcur[tid] = val - h;
    }
    __syncthreads();

    // phase 3: scatter into LDS, record monotonic-per-bucket global targets
#pragma unroll
    for (int k = 0; k < 7; ++k) {
        if (bk[k] >= 0) {
            int b = bk[k];
            int p = atomicAdd(&lcur[b], 1);
            ebuf[p] = (int)pk[k];
            gtgt[p] = gbase[b] + (p - hist[b]);
        }
    }
    __syncthreads();

    // phase 4: slot-ordered drain -> piecewise-coalesced global writes
    for (int i = tid; i < TILE; i += 1024)
        part[gtgt[i]] = ebuf[i];
}

// shared quantize body: one u32 (4 dims) per call
__device__ __forceinline__ void quant_body(int i, const unsigned short* __restrict__ inb,
                                           unsigned char* __restrict__ out8, float s) {
    uint2 v = ((const uint2*)inb)[i];
    float4 f = bf16x4_to_f4(v);
    int q0 = min(127, max(-127, __float2int_rn(f.x * s))) + 128;
    int q1 = min(127, max(-127, __float2int_rn(f.y * s))) + 128;
    int q2 = min(127, max(-127, __float2int_rn(f.z * s))) + 128;
    int q3 = min(127, max(-127, __float2int_rn(f.w * s))) + 128;
    ((unsigned*)out8)[i] = (unsigned)q0 | ((unsigned)q1 << 8) |
                           ((unsigned)q2 << 16) | ((unsigned)q3 << 24);
}

// fold n partials -> all threads get max; thread 0 of the block may publish
__device__ __forceinline__ float fold_partials(const float* __restrict__ partial,
                                               int n, float* red, float* bc) {
    int tid = threadIdx.x;
    float m = 0.0f;
    for (int i = tid; i < n; i += 1024) m = fmaxf(m, partial[i]);
    for (int off = 32; off >= 1; off >>= 1) m = fmaxf(m, __shfl_xor(m, off, 64));
    if ((tid & 63) == 0) red[tid >> 6] = m;
    __syncthreads();
    if (tid == 0) {
        float mm = 0.0f;
#pragma unroll
        for (int w = 0; w < 16; ++w) mm = fmaxf(mm, red[w]);
        *bc = mm;
    }
    __syncthreads();
    return *bc;
}

// ---------------------------------------------------------------------------
// BACK: blocks [0,NB) = per-bucket sort emitting rbeg/rend at slack layout;
//       blocks [NB,NB+QBLKS) = fold x-amax + quantize; last 16 = pack weights.
// ---------------------------------------------------------------------------
__global__ __launch_bounds__(1024) void back(const int* __restrict__ gcnt,
                                             const int* __restrict__ part,
                                             int* __restrict__ rbeg,
                                             int* __restrict__ rend,
                                             int* __restrict__ sorted_src,
                                             const unsigned short* __restrict__ xb,
                                             unsigned char* __restrict__ x8,
                                             const float* __restrict__ partial,
                                             unsigned* __restrict__ amax_store,
                                             const float* __restrict__ wl1,
                                             const float* __restrict__ wr1,
                                             unsigned short* __restrict__ wb1,
                                             const float* __restrict__ wl2,
                                             const float* __restrict__ wr2,
                                             unsigned short* __restrict__ wb2) {
    __shared__ int in_buf[MAXB];
    __shared__ int out_buf[MAXB];
    __shared__ int hist[BNODES];
    __shared__ int exs[BNODES];
    __shared__ int cursor[BNODES];
    __shared__ float red[16];
    __shared__ float bc;

    int tid = threadIdx.x;

    if (blockIdx.x >= NB + QBLKS) {              // prep_w role (16 blocks)
        int i = (blockIdx.x - NB - QBLKS) * 1024 + tid;   // 0..16383
        int j = i & 8191;
        int o = j >> 7, kk = j & 127;
        if (i < 8192) {
            float v = (kk < D) ? wl1[o * D + kk] : wr1[o * D + (kk - D)];
            wb1[j] = f2bf(v);
        } else {
            float v = (kk < D) ? wl2[o * D + kk] : wr2[o * D + (kk - D)];
            wb2[j] = f2bf(v);
        }
        return;
    }

    if (blockIdx.x >= NB) {                      // quant role (fold + quantize)
        float A = fold_partials(partial, CAST_BLKS, red, &bc);
        if (blockIdx.x == NB && tid == 0) *amax_store = __float_as_uint(A);
        float s = (A > 0.0f) ? 127.0f / A : 0.0f;
        int i = (blockIdx.x - NB) * 1024 + tid;
        if (i < N_NODES * D / 4) quant_body(i, xb, x8, s);
        return;
    }

    int k = blockIdx.x;
    int base  = k * CAP;                         // slack layout, no scan
    int count = gcnt[k];

    for (int i = tid; i < BNODES; i += 1024) hist[i] = 0;
    __syncthreads();

    for (int i = tid; i < count; i += 1024) {
        int w = part[base + i];
        in_buf[i] = w;
        atomicAdd(&hist[w & (BNODES - 1)], 1);
    }
    __syncthreads();
    if (tid < 64) {
        int a = hist[2 * tid], b = hist[2 * tid + 1];
        int s = a + b, incl = s;
        for (int off = 1; off < 64; off <<= 1) {
            int t = __shfl_up(incl, off, 64);
            if (tid >= off) incl += t;
        }
        int excl = incl - s;
        exs[2 * tid] = excl;
        exs[2 * tid + 1] = excl + a;
    }
    __syncthreads();
    if (tid < BNODES) {
        int node = k * BNODES + tid;
        if (node < N_NODES) {
            rbeg[node] = base + exs[tid];
            rend[node] = base + exs[tid] + hist[tid];
        }
        cursor[tid] = exs[tid];
    }
    __syncthreads();
    for (int i = tid; i < count; i += 1024) {
        int w = in_buf[i];
        int r = atomicAdd(&cursor[w & (BNODES - 1)], 1);
        out_buf[r] = w >> BSHIFT;
    }
    __syncthreads();
    for (int i = tid; i < count; i += 1024)
        sorted_src[base + i] = out_buf[i];
}

// ---------------------------------------------------------------------------
// Quantize h (folds HPARTS partials itself; block 0 publishes scales[1])
// ---------------------------------------------------------------------------
__global__ __launch_bounds__(1024) void quant8f(const unsigned short* __restrict__ inb,
                                                unsigned char* __restrict__ out8,
                                                const float* __restrict__ partial,
                                                unsigned* __restrict__ amax_store) {
    __shared__ float red[16];
    __shared__ float bc;
    float A = fold_partials(partial, HPARTS, red, &bc);
    if (blockIdx.x == 0 && threadIdx.x == 0) *amax_store = __float_as_uint(A);
    float s = (A > 0.0f) ? 127.0f / A : 0.0f;
    int i = blockIdx.x * 1024 + threadIdx.x;
    if (i < N_NODES * D / 4) quant_body(i, inb, out8, s);
}

// byte extract: (0,b3,0,b1) from w in one v_perm_b32. aLo keeps bytes 0,2 as
// packed u16 lanes; aHi keeps 1,3.
#define ACCW(w, kk) { aLo[kk] += (w) & 0x00FF00FFu; \
                      aHi[kk] += __builtin_amdgcn_perm(0u, (w), 0x04030401u); }
#define ACC4(v) { ACCW((v).x, 0) ACCW((v).y, 1) ACCW((v).z, 2) ACCW((v).w, 3) }

// ---------------------------------------------------------------------------
// Fused SAGE layer v7: PERSISTENT blocks.
// Round-17 lessons: (a) direct per-lane nbr loads (r16) raised vmem count 4x
//     and REGRESSED -> reverted to shfl distribution (1 coalesced load/round);
// (b) counters say latency-bound with no cross-tile overlap: waves hold zero
//     outstanding loads during reduce/dequant/MFMA/store. Now 1024 blocks
//     (4/CU, full occupancy) loop ~6 tiles each; tile t+1's rbeg/rend issue
//     at gather start, its first nbr ids issue during dequant -> the
//     rbeg->nbr stages leave the per-tile critical path (T14 issue-early).
// ---------------------------------------------------------------------------
__global__ __launch_bounds__(512, 8) void sage8(
    const int* __restrict__ rbeg, const int* __restrict__ rend,
    const int* __restrict__ nbr,
    const unsigned char* __restrict__ tab8,     // int8 table, 64 B rows
    const unsigned short* __restrict__ selfb,   // bf16 self rows
    const unsigned* __restrict__ amax_bits,     // gather-table absmax
    const unsigned short* __restrict__ wb,      // packed bf16 weights [64][128]
    const float* __restrict__ b_l,
    float* __restrict__ out,                    // fp32 out (layer 2) or null
    unsigned short* __restrict__ outb,          // bf16 out (layer 1) or null
    float* __restrict__ hpart,                  // per-tile |h| partials or null
    int apply_relu)
{
    __shared__ unsigned short a_s[16][136];   // [node][k] bf16 (row 272 B)
    __shared__ float st[16][68];              // staged outputs (padded rows)
    __shared__ float bias[D];
    __shared__ float wred[4];

    int tid = threadIdx.x;
    if (tid < D) bias[tid] = b_l[tid];

    int wave = tid >> 6;          // 0..7
    int lane = tid & 63;
    int nsel = lane >> 5;         // which of the wave's 2 nodes
    int l32  = lane & 31;
    int g    = l32 >> 2;          // neighbor group 0..7
    int c    = l32 & 3;           // 16-byte chunk of the int8 row
    int arow = wave * 2 + nsel;   // 0..15

    float A  = __uint_as_float(*amax_bits);
    float gs = A * (1.0f / 127.0f);
    unsigned c16 = (unsigned)(c << 4);

    // ---- prologue: load tile 0's range + first-round ids ----
    int tile = blockIdx.x;
    int begin = rbeg[tile * 16 + arow];
    int end   = rend[tile * 16 + arow];
    int id0   = (begin + l32 < end) ? __builtin_nontemporal_load(&nbr[begin + l32]) : 0;

    for (; tile < NT; tile += SGRID) {
        int node = tile * 16 + arow;
        int nt2  = tile + SGRID;

        // issue next tile's range loads NOW (complete during gather)
        int b2 = 0, e2 = 0;
        if (nt2 < NT) {
            b2 = rbeg[nt2 * 16 + arow];
            e2 = rend[nt2 * 16 + arow];
        }

        // early independent self-row load; nt = don't evict table lines
        uint2v xv = {0, 0};
        if (l32 < 16)
            xv = __builtin_nontemporal_load((const uint2v*)&selfb[(size_t)node * D + 4 * l32]);

        unsigned aLo[4] = {0, 0, 0, 0};
        unsigned aHi[4] = {0, 0, 0, 0};
        int idc = id0;
        for (int base = begin; base < end; base += 32) {
            int m = end - base; if (m > 32) m = 32;
            if (base != begin)
                idc = (l32 < m) ? __builtin_nontemporal_load(&nbr[base + l32]) : 0;
            int s0 = __shfl(idc, nsel * 32 + g,      64);
            int s1 = __shfl(idc, nsel * 32 + 8 + g,  64);
            int s2 = __shfl(idc, nsel * 32 + 16 + g, 64);
            int s3 = __shfl(idc, nsel * 32 + 24 + g, 64);
            bool a0 = (g < m), a1 = (8 + g < m), a2 = (16 + g < m), a3 = (24 + g < m);
            uint4 v0, v1, v2, v3;
            if (a0) v0 = *(const uint4*)(tab8 + ((((unsigned)s0) << 6) | c16));
            if (a1) v1 = *(const uint4*)(tab8 + ((((unsigned)s1) << 6) | c16));
            if (a2) v2 = *(const uint4*)(tab8 + ((((unsigned)s2) << 6) | c16));
            if (a3) v3 = *(const uint4*)(tab8 + ((((unsigned)s3) << 6) | c16));
            if (a0) { ACC4(v0) }
            if (a1) { ACC4(v1) }
            if (a2) { ACC4(v2) }
            if (a3) { ACC4(v3) }
        }

        // reduce across the 8 groups (offsets 4,8,16 -- within the 32-lane half)
#pragma unroll
        for (int off = 4; off <= 16; off <<= 1) {
#pragma unroll
            for (int k = 0; k < 4; ++k) {
                aLo[k] += (unsigned)__shfl_xor((int)aLo[k], off, 64);
                aHi[k] += (unsigned)__shfl_xor((int)aHi[k], off, 64);
            }
        }

        // prefetch next tile's first-round ids (b2 arrived during gather);
        // result consumed next iteration -> latency hidden under MFMA+stores
        int id2 = 0;
        if (nt2 < NT && b2 + l32 < e2)
            id2 = __builtin_nontemporal_load(&nbr[b2 + l32]);

        int   deg  = end - begin;
        float invd = 1.0f / fmaxf((float)deg, 1.0f);
        float sc   = gs * invd;
        float nofs = -128.0f * (float)deg * sc;      // fused (-bofs)*sc

        // all-lane dequant: lane (c,g) produces dims 16c+2g, 2g+1 of its node
        {
            unsigned lo01 = (g & 2) ? aLo[1] : aLo[0];
            unsigned lo23 = (g & 2) ? aLo[3] : aLo[2];
            unsigned wLo  = (g & 4) ? lo23 : lo01;
            unsigned hi01 = (g & 2) ? aHi[1] : aHi[0];
            unsigned hi23 = (g & 2) ? aHi[3] : aHi[2];
            unsigned wHi  = (g & 4) ? hi23 : hi01;
            int sh = (g & 1) << 4;
            float d0 = (float)((wLo >> sh) & 0xFFFFu);
            float d1 = (float)((wHi >> sh) & 0xFFFFu);
            float f0 = fmaf(d0, sc, nofs);
            float f1 = fmaf(d1, sc, nofs);
            *(unsigned*)&a_s[arow][16 * c + 2 * g] = cvtpk(f0, f1);
        }
        if (l32 < 16)                   // self row bf16 -> A k=64..127
            *(uint2v*)&a_s[arow][64 + 4 * l32] = xv;
        __syncthreads();                // b1: a_s ready

        if (wave < 4) {
            // ---- MFMA: wave w -> output cols 16w..16w+15 (4 MFMAs) ----
            int quad = lane >> 4;
            int cc   = lane & 15;

            float4v acc = {0.f, 0.f, 0.f, 0.f};
#pragma unroll
            for (int kk = 0; kk < 4; ++kk) {
                short8 af = *(const short8*)&a_s[cc][kk * 32 + quad * 8];
                short8 bf = *(const short8*)(wb + (size_t)(wave * 16 + cc) * 128 + kk * 32 + quad * 8);
                acc = __builtin_amdgcn_mfma_f32_16x16x32_bf16(af, bf, acc, 0, 0, 0);
            }

            int o = wave * 16 + cc;
            float bv = bias[o];
            float vv[4];
#pragma unroll
            for (int r = 0; r < 4; ++r) {
                float v = acc[r] + bv;
                if (apply_relu) v = fmaxf(v, 0.0f);
                vv[r] = v;
                st[quad * 4 + r][o] = v;
            }
            if (hpart) {
                float m = fmaxf(fmaxf(fabsf(vv[0]), fabsf(vv[1])),
                                fmaxf(fabsf(vv[2]), fabsf(vv[3])));
                for (int off = 32; off >= 1; off >>= 1) m = fmaxf(m, __shfl_xor(m, off, 64));
                if (lane == 0) wred[wave] = m;
            }
        }
        __syncthreads();                // b2: st ready

        if (wave >= 4) {                // coalesced full-line stores
            int idx = tid - 256;        // 0..255
            if (outb) {                 // layer 1: bf16, 128 lanes
                if (idx < 128) {
                    int row = idx >> 3, c8 = idx & 7;
                    const float* p = &st[row][c8 * 8];
                    float4v f0 = *(const float4v*)p;
                    float4v f1 = *(const float4v*)(p + 4);
                    uint4v q;
                    q[0] = cvtpk(f0[0], f0[1]); q[1] = cvtpk(f0[2], f0[3]);
                    q[2] = cvtpk(f1[0], f1[1]); q[3] = cvtpk(f1[2], f1[3]);
                    __builtin_nontemporal_store(q,
                        (uint4v*)&outb[((size_t)(tile * 16 + row)) * D + 8 * c8]);
                }
            } else {                    // layer 2: fp32, 256 lanes
                int row = idx >> 4, c4 = idx & 15;
                uint4v q = *(const uint4v*)&st[row][c4 * 4];
                __builtin_nontemporal_store(q,
                    (uint4v*)&out[((size_t)(tile * 16 + row)) * D + 4 * c4]);
            }
            if (hpart && idx == 0)
                hpart[tile] = fmaxf(fmaxf(wred[0], wred[1]), fmaxf(wred[2], wred[3]));
        }

        begin = b2; end = e2; id0 = id2;    // rotate prefetched state
    }
}

// ---------------------------------------------------------------------------
// Launch: 6 dispatches
// ---------------------------------------------------------------------------
extern "C" void kernel_launch(void* const* d_in, const int* in_sizes, int n_in,
                              void* d_out, int out_size, void* d_ws, size_t ws_size,
                              hipStream_t stream) {
    const float* x    = (const float*)d_in[0];
    const int*   ei   = (const int*)d_in[1];   // [2, E]: src = ei, dst = ei + E
    const float* w_l1 = (const float*)d_in[2];
    const float* b_l1 = (const float*)d_in[3];
    const float* w_r1 = (const float*)d_in[4];
    const float* w_l2 = (const float*)d_in[5];
    const float* b_l2 = (const float*)d_in[6];
    const float* w_r2 = (const float*)d_in[7];
    float* out = (float*)d_out;

    const int* src = ei;
    const int* dst = ei + N_EDGES;

    unsigned* scales   = (unsigned*)d_ws;                 // [0]=A_x, [1]=A_h
    int* gcnt          = (int*)d_ws + 4;                  // NB (adjacent: one memset)
    int* rbeg          = gcnt + NB;                       // NPAD
    int* rend          = rbeg + NPAD;                     // NPAD
    int* part          = rend + NPAD;                     // NB*CAP (slack layout)
    int* sorted_src    = part + NB * CAP;                 // NB*CAP (slack layout)
    unsigned short* xb = (unsigned short*)(sorted_src + NB * CAP);  // N*D bf16
    unsigned short* hb = xb + (size_t)N_NODES * D;                  // N*D bf16
    unsigned char* x8  = (unsigned char*)(hb + (size_t)N_NODES * D);// N*D u8
    unsigned char* h8  = x8 + (size_t)N_NODES * D;                  // N*D u8
    unsigned short* wb1 = (unsigned short*)(h8 + (size_t)N_NODES * D); // 64*128
    unsigned short* wb2 = wb1 + D * 2 * D;                             // 64*128
    float* partA       = (float*)(wb2 + D * 2 * D);       // max(CAST_BLKS, HPARTS)

    (void)hipMemsetAsync(d_ws, 0, 16 + NB * sizeof(int), stream);   // scales + gcnt

    front<<<dim3(CAST_BLKS + PB), dim3(1024), 0, stream>>>(x, xb, partA,
                                                           src, dst, gcnt, part);
    back<<<dim3(NB + QBLKS + 16), dim3(1024), 0, stream>>>(gcnt, part,
                                                           rbeg, rend, sorted_src,
                                                           xb, x8, partA, &scales[0],
                                                           w_l1, w_r1, wb1,
                                                           w_l2, w_r2, wb2);

    dim3 lblk(512);
    dim3 lgrid(SGRID);                       // persistent: 4 blocks/CU
    sage8<<<lgrid, lblk, 0, stream>>>(rbeg, rend, sorted_src, x8, xb,
                                      &scales[0], wb1, b_l1,
                                      (float*)nullptr, hb, partA, /*relu=*/1);
    quant8f<<<dim3(QBLKS), dim3(1024), 0, stream>>>(hb, h8, partA, &scales[1]);
    sage8<<<lgrid, lblk, 0, stream>>>(rbeg, rend, sorted_src, h8, hb,
                                      &scales[1], wb2, b_l2,
                                      out, (unsigned short*)nullptr,
                                      (float*)nullptr, /*relu=*/0);
}

// Round 10
// 210.202 us; speedup vs baseline: 1.2346x; 1.2346x over previous
//
#include <hip/hip_runtime.h>

#define N_NODES 100000
#define N_EDGES 1600000
#define D 64

#define BSHIFT 7                                   // 128 nodes per bucket
#define BNODES (1 << BSHIFT)                       // 128
#define NB ((N_NODES + BNODES - 1) / BNODES)       // 782 buckets
#define NPAD (NB * BNODES)                         // 100096 (padded node count)
#define PB 256                                     // partition blocks
#define TILE ((N_EDGES + PB - 1) / PB)             // 6250 edges per block (exact)
#define CAP 2432                                   // slack per bucket (mean 2046 + 8.5 sigma)
#define MAXB 4096
#define CAST_BLKS 512                              // cast blocks inside `front`
#define QBLKS ((N_NODES * D / 4 + 1023) / 1024)    // 1563 quant blocks (1024 thr)
#define NT (N_NODES / 16)                          // 6250 node-tiles
#define HPARTS NT                                  // per-tile h-absmax partials

typedef __attribute__((ext_vector_type(8))) short short8;   // 8 bf16 (4 VGPRs)
typedef __attribute__((ext_vector_type(4))) float float4v;  // MFMA acc
typedef __attribute__((ext_vector_type(2))) unsigned uint2v; // clang vector (nt ok)
typedef __attribute__((ext_vector_type(4))) unsigned uint4v; // clang vector (nt ok)

// round-to-nearest-even fp32 -> bf16 bits (scalar path)
__device__ __forceinline__ unsigned short f2bf(float f) {
    unsigned u = __float_as_uint(f);
    u = (u + 0x7fffu + ((u >> 16) & 1u)) >> 16;
    return (unsigned short)u;
}
// HW packed conversion: dst = [bf16(a) | bf16(b)<<16] in ONE VALU op
__device__ __forceinline__ unsigned cvtpk(float a, float b) {
    unsigned r;
    asm("v_cvt_pk_bf16_f32 %0, %1, %2" : "=v"(r) : "v"(a), "v"(b));
    return r;
}

__device__ __forceinline__ float4 bf16x4_to_f4(uint2 v) {
    float4 r;
    r.x = __uint_as_float(v.x << 16);
    r.y = __uint_as_float(v.x & 0xffff0000u);
    r.z = __uint_as_float(v.y << 16);
    r.w = __uint_as_float(v.y & 0xffff0000u);
    return r;
}

// ---------------------------------------------------------------------------
// FRONT: blocks [0,CAST_BLKS) = cast x->bf16 + partial absmax (grid-stride);
//        blocks [CAST_BLKS, CAST_BLKS+PB) = fused edge partition with
//        LDS-staged coalesced output. Round-18: 1024-ladder scan (10 barriers)
//        replaced by wave-hierarchical shfl scan (2 barriers).
// ---------------------------------------------------------------------------
__global__ __launch_bounds__(1024) void front(const float* __restrict__ x,
                                              unsigned short* __restrict__ xb,
                                              float* __restrict__ partial,
                                              const int* __restrict__ src,
                                              const int* __restrict__ dst,
                                              int* __restrict__ gcnt,
                                              int* __restrict__ part) {
    __shared__ float red[16];
    __shared__ int hist[NB];      // counts -> lbase
    __shared__ int lcur[NB];      // LDS scatter cursors
    __shared__ int gbase[NB];     // per-bucket global base
    __shared__ int wsum[16];      // wave sums for hierarchical scan
    __shared__ int ebuf[TILE];    // staged packed edges
    __shared__ int gtgt[TILE];    // per-slot global target

    int tid = threadIdx.x;

    if (blockIdx.x < CAST_BLKS) {
        float m = 0.0f;
        int stride = CAST_BLKS * 1024;
        for (int i = blockIdx.x * 1024 + tid; i < N_NODES * D / 4; i += stride) {
            float4 v = ((const float4*)x)[i];
            ushort4 o;
            o.x = f2bf(v.x); o.y = f2bf(v.y); o.z = f2bf(v.z); o.w = f2bf(v.w);
            ((ushort4*)xb)[i] = o;
            m = fmaxf(m, fmaxf(fmaxf(fabsf(v.x), fabsf(v.y)), fmaxf(fabsf(v.z), fabsf(v.w))));
        }
        for (int off = 32; off >= 1; off >>= 1) m = fmaxf(m, __shfl_xor(m, off, 64));
        if ((tid & 63) == 0) red[tid >> 6] = m;
        __syncthreads();
        if (tid == 0) {
            float mm = 0.0f;
#pragma unroll
            for (int w = 0; w < 16; ++w) mm = fmaxf(mm, red[w]);
            partial[blockIdx.x] = mm;
        }
        return;
    }

    // ---- partition: count -> reserve -> LDS scatter -> coalesced drain ----
    int bid = blockIdx.x - CAST_BLKS;
    for (int i = tid; i < NB; i += 1024) hist[i] = 0;
    __syncthreads();

    int lo = bid * TILE;                  // 256*6250 == N_EDGES, no tail

    unsigned pk[7];
    int bk[7];
#pragma unroll
    for (int k = 0; k < 7; ++k) {
        int e = lo + tid + k * 1024;
        if (tid + k * 1024 < TILE) {
            int dd = dst[e];
            int ss = src[e];
            int b = dd >> BSHIFT;
            pk[k] = ((unsigned)ss << BSHIFT) | (unsigned)(dd & (BNODES - 1));
            bk[k] = b;
            atomicAdd(&hist[b], 1);
        } else {
            bk[k] = -1;
        }
    }
    __syncthreads();

    // phase 2: global reservation + wave-hierarchical exclusive scan (2 bar)
    int lane = tid & 63, wid = tid >> 6;
    int h = (tid < NB) ? hist[tid] : 0;
    if (tid < NB)
        gbase[tid] = tid * CAP + (h ? atomicAdd(&gcnt[tid], h) : 0);
    int incl = h;
#pragma unroll
    for (int off = 1; off < 64; off <<= 1) {
        int t = __shfl_up(incl, off, 64);
        if (lane >= off) incl += t;
    }
    if (lane == 63) wsum[wid] = incl;
    __syncthreads();
    if (wid == 0 && lane < 16) {
        int s = wsum[lane], sincl = s;
#pragma unroll
        for (int off = 1; off < 16; off <<= 1) {
            int t = __shfl_up(sincl, off, 64);
            if (lane >= off) sincl += t;
        }
        wsum[lane] = sincl - s;           // exclusive wave offset
    }
    __syncthreads();
    if (tid < NB) {
        int excl = incl - h + wsum[wid];
        hist[tid] = excl;                 // lbase
        lcur[tid] = excl;
    }
    __syncthreads();

    // phase 3: scatter into LDS, record monotonic-per-bucket global targets
#pragma unroll
    for (int k = 0; k < 7; ++k) {
        if (bk[k] >= 0) {
            int b = bk[k];
            int p = atomicAdd(&lcur[b], 1);
            ebuf[p] = (int)pk[k];
            gtgt[p] = gbase[b] + (p - hist[b]);
        }
    }
    __syncthreads();

    // phase 4: slot-ordered drain -> piecewise-coalesced global writes
    for (int i = tid; i < TILE; i += 1024)
        part[gtgt[i]] = ebuf[i];
}

// shared quantize body: one u32 (4 dims) per call
__device__ __forceinline__ void quant_body(int i, const unsigned short* __restrict__ inb,
                                           unsigned char* __restrict__ out8, float s) {
    uint2 v = ((const uint2*)inb)[i];
    float4 f = bf16x4_to_f4(v);
    int q0 = min(127, max(-127, __float2int_rn(f.x * s))) + 128;
    int q1 = min(127, max(-127, __float2int_rn(f.y * s))) + 128;
    int q2 = min(127, max(-127, __float2int_rn(f.z * s))) + 128;
    int q3 = min(127, max(-127, __float2int_rn(f.w * s))) + 128;
    ((unsigned*)out8)[i] = (unsigned)q0 | ((unsigned)q1 << 8) |
                           ((unsigned)q2 << 16) | ((unsigned)q3 << 24);
}

// fold n partials -> all threads get max; thread 0 of the block may publish
__device__ __forceinline__ float fold_partials(const float* __restrict__ partial,
                                               int n, float* red, float* bc) {
    int tid = threadIdx.x;
    float m = 0.0f;
    for (int i = tid; i < n; i += 1024) m = fmaxf(m, partial[i]);
    for (int off = 32; off >= 1; off >>= 1) m = fmaxf(m, __shfl_xor(m, off, 64));
    if ((tid & 63) == 0) red[tid >> 6] = m;
    __syncthreads();
    if (tid == 0) {
        float mm = 0.0f;
#pragma unroll
        for (int w = 0; w < 16; ++w) mm = fmaxf(mm, red[w]);
        *bc = mm;
    }
    __syncthreads();
    return *bc;
}

// ---------------------------------------------------------------------------
// BACK: blocks [0,NB) = per-bucket sort emitting rbeg/rend at slack layout;
//       blocks [NB,NB+QBLKS) = fold x-amax + quantize; last 16 = pack weights.
// ---------------------------------------------------------------------------
__global__ __launch_bounds__(1024) void back(const int* __restrict__ gcnt,
                                             const int* __restrict__ part,
                                             int* __restrict__ rbeg,
                                             int* __restrict__ rend,
                                             int* __restrict__ sorted_src,
                                             const unsigned short* __restrict__ xb,
                                             unsigned char* __restrict__ x8,
                                             const float* __restrict__ partial,
                                             unsigned* __restrict__ amax_store,
                                             const float* __restrict__ wl1,
                                             const float* __restrict__ wr1,
                                             unsigned short* __restrict__ wb1,
                                             const float* __restrict__ wl2,
                                             const float* __restrict__ wr2,
                                             unsigned short* __restrict__ wb2) {
    __shared__ int in_buf[MAXB];
    __shared__ int out_buf[MAXB];
    __shared__ int hist[BNODES];
    __shared__ int exs[BNODES];
    __shared__ int cursor[BNODES];
    __shared__ float red[16];
    __shared__ float bc;

    int tid = threadIdx.x;

    if (blockIdx.x >= NB + QBLKS) {              // prep_w role (16 blocks)
        int i = (blockIdx.x - NB - QBLKS) * 1024 + tid;   // 0..16383
        int j = i & 8191;
        int o = j >> 7, kk = j & 127;
        if (i < 8192) {
            float v = (kk < D) ? wl1[o * D + kk] : wr1[o * D + (kk - D)];
            wb1[j] = f2bf(v);
        } else {
            float v = (kk < D) ? wl2[o * D + kk] : wr2[o * D + (kk - D)];
            wb2[j] = f2bf(v);
        }
        return;
    }

    if (blockIdx.x >= NB) {                      // quant role (fold + quantize)
        float A = fold_partials(partial, CAST_BLKS, red, &bc);
        if (blockIdx.x == NB && tid == 0) *amax_store = __float_as_uint(A);
        float s = (A > 0.0f) ? 127.0f / A : 0.0f;
        int i = (blockIdx.x - NB) * 1024 + tid;
        if (i < N_NODES * D / 4) quant_body(i, xb, x8, s);
        return;
    }

    int k = blockIdx.x;
    int base  = k * CAP;                         // slack layout, no scan
    int count = gcnt[k];

    for (int i = tid; i < BNODES; i += 1024) hist[i] = 0;
    __syncthreads();

    for (int i = tid; i < count; i += 1024) {
        int w = part[base + i];
        in_buf[i] = w;
        atomicAdd(&hist[w & (BNODES - 1)], 1);
    }
    __syncthreads();
    if (tid < 64) {
        int a = hist[2 * tid], b = hist[2 * tid + 1];
        int s = a + b, incl = s;
        for (int off = 1; off < 64; off <<= 1) {
            int t = __shfl_up(incl, off, 64);
            if (tid >= off) incl += t;
        }
        int excl = incl - s;
        exs[2 * tid] = excl;
        exs[2 * tid + 1] = excl + a;
    }
    __syncthreads();
    if (tid < BNODES) {
        int node = k * BNODES + tid;
        if (node < N_NODES) {
            rbeg[node] = base + exs[tid];
            rend[node] = base + exs[tid] + hist[tid];
        }
        cursor[tid] = exs[tid];
    }
    __syncthreads();
    for (int i = tid; i < count; i += 1024) {
        int w = in_buf[i];
        int r = atomicAdd(&cursor[w & (BNODES - 1)], 1);
        out_buf[r] = w >> BSHIFT;
    }
    __syncthreads();
    for (int i = tid; i < count; i += 1024)
        sorted_src[base + i] = out_buf[i];
}

// ---------------------------------------------------------------------------
// Quantize h (folds HPARTS partials itself; block 0 publishes scales[1])
// ---------------------------------------------------------------------------
__global__ __launch_bounds__(1024) void quant8f(const unsigned short* __restrict__ inb,
                                                unsigned char* __restrict__ out8,
                                                const float* __restrict__ partial,
                                                unsigned* __restrict__ amax_store) {
    __shared__ float red[16];
    __shared__ float bc;
    float A = fold_partials(partial, HPARTS, red, &bc);
    if (blockIdx.x == 0 && threadIdx.x == 0) *amax_store = __float_as_uint(A);
    float s = (A > 0.0f) ? 127.0f / A : 0.0f;
    int i = blockIdx.x * 1024 + threadIdx.x;
    if (i < N_NODES * D / 4) quant_body(i, inb, out8, s);
}

// byte extract: (0,b3,0,b1) from w in one v_perm_b32. aLo keeps bytes 0,2 as
// packed u16 lanes; aHi keeps 1,3.
#define ACCW(w, kk) { aLo[kk] += (w) & 0x00FF00FFu; \
                      aHi[kk] += __builtin_amdgcn_perm(0u, (w), 0x04030401u); }
#define ACC4(v) { ACCW((v).x, 0) ACCW((v).y, 1) ACCW((v).z, 2) ACCW((v).w, 3) }

// ---------------------------------------------------------------------------
// Fused SAGE layer v8 = round-6 structure restored (best measured: 41.6 us).
// Round-17/18 lessons locked in comments:
//  - direct per-lane nbr loads (r16): 4x vmem count, REGRESSED. Keep shfl.
//  - persistent blocks + prefetch (r17): destroyed L2 locality of the
//    sequential tile schedule (FETCH 76->162 MB, WRITE 13->54 MB), traffic-
//    bound regression. Keep 6250 sequential blocks.
// ---------------------------------------------------------------------------
__global__ __launch_bounds__(512, 8) void sage8(
    const int* __restrict__ rbeg, const int* __restrict__ rend,
    const int* __restrict__ nbr,
    const unsigned char* __restrict__ tab8,     // int8 table, 64 B rows
    const unsigned short* __restrict__ selfb,   // bf16 self rows
    const unsigned* __restrict__ amax_bits,     // gather-table absmax
    const unsigned short* __restrict__ wb,      // packed bf16 weights [64][128]
    const float* __restrict__ b_l,
    float* __restrict__ out,                    // fp32 out (layer 2) or null
    unsigned short* __restrict__ outb,          // bf16 out (layer 1) or null
    float* __restrict__ hpart,                  // per-tile |h| partials or null
    int apply_relu)
{
    __shared__ unsigned short a_s[16][136];   // [node][k] bf16 (row 272 B)
    __shared__ float st[16][68];              // staged outputs (padded rows)
    __shared__ float bias[D];
    __shared__ float wred[4];

    int tid = threadIdx.x;
    if (tid < D) bias[tid] = b_l[tid];

    int wave = tid >> 6;          // 0..7
    int lane = tid & 63;
    int nsel = lane >> 5;         // which of the wave's 2 nodes
    int l32  = lane & 31;
    int g    = l32 >> 2;          // neighbor group 0..7
    int c    = l32 & 3;           // 16-byte chunk of the int8 row
    int arow = wave * 2 + nsel;   // 0..15
    int node = blockIdx.x * 16 + arow;   // N_NODES = 6250*16, no tail

    float A  = __uint_as_float(*amax_bits);
    float gs = A * (1.0f / 127.0f);

    int begin = rbeg[node];
    int end   = rend[node];

    // early independent self-row load; nt = don't evict table lines
    uint2v xv = {0, 0};
    if (l32 < 16)
        xv = __builtin_nontemporal_load((const uint2v*)&selfb[(size_t)node * D + 4 * l32]);

    unsigned c16 = (unsigned)(c << 4);
    unsigned aLo[4] = {0, 0, 0, 0};
    unsigned aHi[4] = {0, 0, 0, 0};
    for (int base = begin; base < end; base += 32) {
        int m = end - base; if (m > 32) m = 32;
        int id = (l32 < m) ? __builtin_nontemporal_load(&nbr[base + l32]) : 0;
        int s0 = __shfl(id, nsel * 32 + g,      64);
        int s1 = __shfl(id, nsel * 32 + 8 + g,  64);
        int s2 = __shfl(id, nsel * 32 + 16 + g, 64);
        int s3 = __shfl(id, nsel * 32 + 24 + g, 64);
        bool a0 = (g < m), a1 = (8 + g < m), a2 = (16 + g < m), a3 = (24 + g < m);
        uint4 v0, v1, v2, v3;
        if (a0) v0 = *(const uint4*)(tab8 + ((((unsigned)s0) << 6) | c16));
        if (a1) v1 = *(const uint4*)(tab8 + ((((unsigned)s1) << 6) | c16));
        if (a2) v2 = *(const uint4*)(tab8 + ((((unsigned)s2) << 6) | c16));
        if (a3) v3 = *(const uint4*)(tab8 + ((((unsigned)s3) << 6) | c16));
        if (a0) { ACC4(v0) }
        if (a1) { ACC4(v1) }
        if (a2) { ACC4(v2) }
        if (a3) { ACC4(v3) }
    }

    // reduce across the 8 groups (offsets 4,8,16 -- within the 32-lane half)
#pragma unroll
    for (int off = 4; off <= 16; off <<= 1) {
#pragma unroll
        for (int k = 0; k < 4; ++k) {
            aLo[k] += (unsigned)__shfl_xor((int)aLo[k], off, 64);
            aHi[k] += (unsigned)__shfl_xor((int)aHi[k], off, 64);
        }
    }

    int   deg  = end - begin;
    float invd = 1.0f / fmaxf((float)deg, 1.0f);
    float sc   = gs * invd;
    float nofs = -128.0f * (float)deg * sc;      // fused (-bofs)*sc

    // all-lane dequant: lane (c,g) produces dims 16c+2g, 2g+1 of its node
    {
        unsigned lo01 = (g & 2) ? aLo[1] : aLo[0];
        unsigned lo23 = (g & 2) ? aLo[3] : aLo[2];
        unsigned wLo  = (g & 4) ? lo23 : lo01;
        unsigned hi01 = (g & 2) ? aHi[1] : aHi[0];
        unsigned hi23 = (g & 2) ? aHi[3] : aHi[2];
        unsigned wHi  = (g & 4) ? hi23 : hi01;
        int sh = (g & 1) << 4;
        float d0 = (float)((wLo >> sh) & 0xFFFFu);
        float d1 = (float)((wHi >> sh) & 0xFFFFu);
        float f0 = fmaf(d0, sc, nofs);
        float f1 = fmaf(d1, sc, nofs);
        *(unsigned*)&a_s[arow][16 * c + 2 * g] = cvtpk(f0, f1);
    }
    if (l32 < 16)                   // self row bf16 -> A k=64..127
        *(uint2v*)&a_s[arow][64 + 4 * l32] = xv;
    __syncthreads();                // b1: a_s ready

    if (wave < 4) {
        // ---- MFMA: wave w -> output cols 16w..16w+15 (4 MFMAs) ----
        int quad = lane >> 4;
        int cc   = lane & 15;

        float4v acc = {0.f, 0.f, 0.f, 0.f};
#pragma unroll
        for (int kk = 0; kk < 4; ++kk) {
            short8 af = *(const short8*)&a_s[cc][kk * 32 + quad * 8];
            short8 bf = *(const short8*)(wb + (size_t)(wave * 16 + cc) * 128 + kk * 32 + quad * 8);
            acc = __builtin_amdgcn_mfma_f32_16x16x32_bf16(af, bf, acc, 0, 0, 0);
        }

        int o = wave * 16 + cc;
        float bv = bias[o];
        float vv[4];
#pragma unroll
        for (int r = 0; r < 4; ++r) {
            float v = acc[r] + bv;
            if (apply_relu) v = fmaxf(v, 0.0f);
            vv[r] = v;
            st[quad * 4 + r][o] = v;
        }
        if (hpart) {
            float m = fmaxf(fmaxf(fabsf(vv[0]), fabsf(vv[1])),
                            fmaxf(fabsf(vv[2]), fabsf(vv[3])));
            for (int off = 32; off >= 1; off >>= 1) m = fmaxf(m, __shfl_xor(m, off, 64));
            if (lane == 0) wred[wave] = m;
        }
    }
    __syncthreads();                // b2: st ready

    if (wave >= 4) {                // coalesced full-line stores
        int idx = tid - 256;        // 0..255
        if (outb) {                 // layer 1: bf16, 128 lanes
            if (idx < 128) {
                int row = idx >> 3, c8 = idx & 7;
                const float* p = &st[row][c8 * 8];
                float4v f0 = *(const float4v*)p;
                float4v f1 = *(const float4v*)(p + 4);
                uint4v q;
                q[0] = cvtpk(f0[0], f0[1]); q[1] = cvtpk(f0[2], f0[3]);
                q[2] = cvtpk(f1[0], f1[1]); q[3] = cvtpk(f1[2], f1[3]);
                __builtin_nontemporal_store(q,
                    (uint4v*)&outb[((size_t)(blockIdx.x * 16 + row)) * D + 8 * c8]);
            }
        } else {                    // layer 2: fp32, 256 lanes
            int row = idx >> 4, c4 = idx & 15;
            uint4v q = *(const uint4v*)&st[row][c4 * 4];
            __builtin_nontemporal_store(q,
                (uint4v*)&out[((size_t)(blockIdx.x * 16 + row)) * D + 4 * c4]);
        }
        if (hpart && idx == 0)
            hpart[blockIdx.x] = fmaxf(fmaxf(wred[0], wred[1]), fmaxf(wred[2], wred[3]));
    }
}

// ---------------------------------------------------------------------------
// Launch: 6 dispatches
// ---------------------------------------------------------------------------
extern "C" void kernel_launch(void* const* d_in, const int* in_sizes, int n_in,
                              void* d_out, int out_size, void* d_ws, size_t ws_size,
                              hipStream_t stream) {
    const float* x    = (const float*)d_in[0];
    const int*   ei   = (const int*)d_in[1];   // [2, E]: src = ei, dst = ei + E
    const float* w_l1 = (const float*)d_in[2];
    const float* b_l1 = (const float*)d_in[3];
    const float* w_r1 = (const float*)d_in[4];
    const float* w_l2 = (const float*)d_in[5];
    const float* b_l2 = (const float*)d_in[6];
    const float* w_r2 = (const float*)d_in[7];
    float* out = (float*)d_out;

    const int* src = ei;
    const int* dst = ei + N_EDGES;

    unsigned* scales   = (unsigned*)d_ws;                 // [0]=A_x, [1]=A_h
    int* gcnt          = (int*)d_ws + 4;                  // NB (adjacent: one memset)
    int* rbeg          = gcnt + NB;                       // NPAD
    int* rend          = rbeg + NPAD;                     // NPAD
    int* part          = rend + NPAD;                     // NB*CAP (slack layout)
    int* sorted_src    = part + NB * CAP;                 // NB*CAP (slack layout)
    unsigned short* xb = (unsigned short*)(sorted_src + NB * CAP);  // N*D bf16
    unsigned short* hb = xb + (size_t)N_NODES * D;                  // N*D bf16
    unsigned char* x8  = (unsigned char*)(hb + (size_t)N_NODES * D);// N*D u8
    unsigned char* h8  = x8 + (size_t)N_NODES * D;                  // N*D u8
    unsigned short* wb1 = (unsigned short*)(h8 + (size_t)N_NODES * D); // 64*128
    unsigned short* wb2 = wb1 + D * 2 * D;                             // 64*128
    float* partA       = (float*)(wb2 + D * 2 * D);       // max(CAST_BLKS, HPARTS)

    (void)hipMemsetAsync(d_ws, 0, 16 + NB * sizeof(int), stream);   // scales + gcnt

    front<<<dim3(CAST_BLKS + PB), dim3(1024), 0, stream>>>(x, xb, partA,
                                                           src, dst, gcnt, part);
    back<<<dim3(NB + QBLKS + 16), dim3(1024), 0, stream>>>(gcnt, part,
                                                           rbeg, rend, sorted_src,
                                                           xb, x8, partA, &scales[0],
                                                           w_l1, w_r1, wb1,
                                                           w_l2, w_r2, wb2);

    dim3 lblk(512);
    dim3 lgrid(NT);                          // 6250 sequential tiles
    sage8<<<lgrid, lblk, 0, stream>>>(rbeg, rend, sorted_src, x8, xb,
                                      &scales[0], wb1, b_l1,
                                      (float*)nullptr, hb, partA, /*relu=*/1);
    quant8f<<<dim3(QBLKS), dim3(1024), 0, stream>>>(hb, h8, partA, &scales[1]);
    sage8<<<lgrid, lblk, 0, stream>>>(rbeg, rend, sorted_src, h8, hb,
                                      &scales[1], wb2, b_l2,
                                      out, (unsigned short*)nullptr,
                                      (float*)nullptr, /*relu=*/0);
}

// Round 11
// 201.778 us; speedup vs baseline: 1.2862x; 1.0417x over previous
//
#include <hip/hip_runtime.h>

#define N_NODES 100000
#define N_EDGES 1600000
#define D 64

#define BSHIFT 7                                   // 128 nodes per bucket
#define BNODES (1 << BSHIFT)                       // 128
#define NB ((N_NODES + BNODES - 1) / BNODES)       // 782 buckets
#define NPAD (NB * BNODES)                         // 100096 (padded node count)
#define PB 256                                     // partition blocks
#define TILE ((N_EDGES + PB - 1) / PB)             // 6250 edges per block (exact)
#define CAP 2432                                   // slack per bucket (mean 2046 + 8.5 sigma)
#define MAXB 4096
#define CAST_BLKS 512                              // cast blocks inside `front`
#define NQ16 (N_NODES * D / 16)                    // 400000 16-dim quant items
#define QBLKS16 ((NQ16 + 1023) / 1024)             // 391 quant blocks (16 dims/thr)
#define NT (N_NODES / 16)                          // 6250 node-tiles
#define HPARTS NT                                  // per-tile h-absmax partials

typedef __attribute__((ext_vector_type(8))) short short8;   // 8 bf16 (4 VGPRs)
typedef __attribute__((ext_vector_type(4))) float float4v;  // MFMA acc
typedef __attribute__((ext_vector_type(2))) unsigned uint2v; // clang vector (nt ok)
typedef __attribute__((ext_vector_type(4))) unsigned uint4v; // clang vector (nt ok)

// round-to-nearest-even fp32 -> bf16 bits (scalar path)
__device__ __forceinline__ unsigned short f2bf(float f) {
    unsigned u = __float_as_uint(f);
    u = (u + 0x7fffu + ((u >> 16) & 1u)) >> 16;
    return (unsigned short)u;
}
// HW packed conversion: dst = [bf16(a) | bf16(b)<<16] in ONE VALU op
__device__ __forceinline__ unsigned cvtpk(float a, float b) {
    unsigned r;
    asm("v_cvt_pk_bf16_f32 %0, %1, %2" : "=v"(r) : "v"(a), "v"(b));
    return r;
}

__device__ __forceinline__ float4 bf16x4_to_f4(uint2 v) {
    float4 r;
    r.x = __uint_as_float(v.x << 16);
    r.y = __uint_as_float(v.x & 0xffff0000u);
    r.z = __uint_as_float(v.y << 16);
    r.w = __uint_as_float(v.y & 0xffff0000u);
    return r;
}

// ---------------------------------------------------------------------------
// FRONT: blocks [0,CAST_BLKS) = cast x->bf16 + partial absmax (grid-stride);
//        blocks [CAST_BLKS, CAST_BLKS+PB) = fused edge partition with
//        LDS-staged coalesced output + wave-hierarchical scan.
// ---------------------------------------------------------------------------
__global__ __launch_bounds__(1024) void front(const float* __restrict__ x,
                                              unsigned short* __restrict__ xb,
                                              float* __restrict__ partial,
                                              const int* __restrict__ src,
                                              const int* __restrict__ dst,
                                              int* __restrict__ gcnt,
                                              int* __restrict__ part) {
    __shared__ float red[16];
    __shared__ int hist[NB];      // counts -> lbase
    __shared__ int lcur[NB];      // LDS scatter cursors
    __shared__ int gbase[NB];     // per-bucket global base
    __shared__ int wsum[16];      // wave sums for hierarchical scan
    __shared__ int ebuf[TILE];    // staged packed edges
    __shared__ int gtgt[TILE];    // per-slot global target

    int tid = threadIdx.x;

    if (blockIdx.x < CAST_BLKS) {
        float m = 0.0f;
        int stride = CAST_BLKS * 1024;
        for (int i = blockIdx.x * 1024 + tid; i < N_NODES * D / 4; i += stride) {
            float4 v = ((const float4*)x)[i];
            ushort4 o;
            o.x = f2bf(v.x); o.y = f2bf(v.y); o.z = f2bf(v.z); o.w = f2bf(v.w);
            ((ushort4*)xb)[i] = o;
            m = fmaxf(m, fmaxf(fmaxf(fabsf(v.x), fabsf(v.y)), fmaxf(fabsf(v.z), fabsf(v.w))));
        }
        for (int off = 32; off >= 1; off >>= 1) m = fmaxf(m, __shfl_xor(m, off, 64));
        if ((tid & 63) == 0) red[tid >> 6] = m;
        __syncthreads();
        if (tid == 0) {
            float mm = 0.0f;
#pragma unroll
            for (int w = 0; w < 16; ++w) mm = fmaxf(mm, red[w]);
            partial[blockIdx.x] = mm;
        }
        return;
    }

    // ---- partition: count -> reserve -> LDS scatter -> coalesced drain ----
    int bid = blockIdx.x - CAST_BLKS;
    for (int i = tid; i < NB; i += 1024) hist[i] = 0;
    __syncthreads();

    int lo = bid * TILE;                  // 256*6250 == N_EDGES, no tail

    unsigned pk[7];
    int bk[7];
#pragma unroll
    for (int k = 0; k < 7; ++k) {
        int e = lo + tid + k * 1024;
        if (tid + k * 1024 < TILE) {
            int dd = dst[e];
            int ss = src[e];
            int b = dd >> BSHIFT;
            pk[k] = ((unsigned)ss << BSHIFT) | (unsigned)(dd & (BNODES - 1));
            bk[k] = b;
            atomicAdd(&hist[b], 1);
        } else {
            bk[k] = -1;
        }
    }
    __syncthreads();

    // phase 2: global reservation + wave-hierarchical exclusive scan (2 bar)
    int lane = tid & 63, wid = tid >> 6;
    int h = (tid < NB) ? hist[tid] : 0;
    if (tid < NB)
        gbase[tid] = tid * CAP + (h ? atomicAdd(&gcnt[tid], h) : 0);
    int incl = h;
#pragma unroll
    for (int off = 1; off < 64; off <<= 1) {
        int t = __shfl_up(incl, off, 64);
        if (lane >= off) incl += t;
    }
    if (lane == 63) wsum[wid] = incl;
    __syncthreads();
    if (wid == 0 && lane < 16) {
        int s = wsum[lane], sincl = s;
#pragma unroll
        for (int off = 1; off < 16; off <<= 1) {
            int t = __shfl_up(sincl, off, 64);
            if (lane >= off) sincl += t;
        }
        wsum[lane] = sincl - s;           // exclusive wave offset
    }
    __syncthreads();
    if (tid < NB) {
        int excl = incl - h + wsum[wid];
        hist[tid] = excl;                 // lbase
        lcur[tid] = excl;
    }
    __syncthreads();

    // phase 3: scatter into LDS, record monotonic-per-bucket global targets
#pragma unroll
    for (int k = 0; k < 7; ++k) {
        if (bk[k] >= 0) {
            int b = bk[k];
            int p = atomicAdd(&lcur[b], 1);
            ebuf[p] = (int)pk[k];
            gtgt[p] = gbase[b] + (p - hist[b]);
        }
    }
    __syncthreads();

    // phase 4: slot-ordered drain -> piecewise-coalesced global writes
    for (int i = tid; i < TILE; i += 1024)
        part[gtgt[i]] = ebuf[i];
}

// quantize 16 dims: 4x uint2 bf16 loads -> one uint4v (16 x u8) nt store.
// Round-19: 1 u32/thread made quant launches scheduling-bound (1563 blocks
// for 8 VALU ops each); now 16 dims/thread, 391 blocks.
__device__ __forceinline__ void quant16(int i, const unsigned short* __restrict__ inb,
                                        unsigned char* __restrict__ out8, float s) {
    const uint2* p = (const uint2*)inb + 4 * i;
    uint4v q;
#pragma unroll
    for (int k = 0; k < 4; ++k) {
        float4 f = bf16x4_to_f4(p[k]);
        int q0 = min(127, max(-127, __float2int_rn(f.x * s))) + 128;
        int q1 = min(127, max(-127, __float2int_rn(f.y * s))) + 128;
        int q2 = min(127, max(-127, __float2int_rn(f.z * s))) + 128;
        int q3 = min(127, max(-127, __float2int_rn(f.w * s))) + 128;
        q[k] = (unsigned)q0 | ((unsigned)q1 << 8) |
               ((unsigned)q2 << 16) | ((unsigned)q3 << 24);
    }
    __builtin_nontemporal_store(q, (uint4v*)out8 + i);
}

// fold n partials -> all threads get max; thread 0 of the block may publish
__device__ __forceinline__ float fold_partials(const float* __restrict__ partial,
                                               int n, float* red, float* bc) {
    int tid = threadIdx.x;
    float m = 0.0f;
    for (int i = tid; i < n; i += 1024) m = fmaxf(m, partial[i]);
    for (int off = 32; off >= 1; off >>= 1) m = fmaxf(m, __shfl_xor(m, off, 64));
    if ((tid & 63) == 0) red[tid >> 6] = m;
    __syncthreads();
    if (tid == 0) {
        float mm = 0.0f;
#pragma unroll
        for (int w = 0; w < 16; ++w) mm = fmaxf(mm, red[w]);
        *bc = mm;
    }
    __syncthreads();
    return *bc;
}

// ---------------------------------------------------------------------------
// BACK: blocks [0,NB) = per-bucket sort emitting rbeg/rend at slack layout;
//       blocks [NB,NB+QBLKS16) = fold x-amax + quantize (16 dims/thread);
//       last 16 = pack weights.
// ---------------------------------------------------------------------------
__global__ __launch_bounds__(1024) void back(const int* __restrict__ gcnt,
                                             const int* __restrict__ part,
                                             int* __restrict__ rbeg,
                                             int* __restrict__ rend,
                                             int* __restrict__ sorted_src,
                                             const unsigned short* __restrict__ xb,
                                             unsigned char* __restrict__ x8,
                                             const float* __restrict__ partial,
                                             unsigned* __restrict__ amax_store,
                                             const float* __restrict__ wl1,
                                             const float* __restrict__ wr1,
                                             unsigned short* __restrict__ wb1,
                                             const float* __restrict__ wl2,
                                             const float* __restrict__ wr2,
                                             unsigned short* __restrict__ wb2) {
    __shared__ int in_buf[MAXB];
    __shared__ int out_buf[MAXB];
    __shared__ int hist[BNODES];
    __shared__ int exs[BNODES];
    __shared__ int cursor[BNODES];
    __shared__ float red[16];
    __shared__ float bc;

    int tid = threadIdx.x;

    if (blockIdx.x >= NB + QBLKS16) {            // prep_w role (16 blocks)
        int i = (blockIdx.x - NB - QBLKS16) * 1024 + tid;   // 0..16383
        int j = i & 8191;
        int o = j >> 7, kk = j & 127;
        if (i < 8192) {
            float v = (kk < D) ? wl1[o * D + kk] : wr1[o * D + (kk - D)];
            wb1[j] = f2bf(v);
        } else {
            float v = (kk < D) ? wl2[o * D + kk] : wr2[o * D + (kk - D)];
            wb2[j] = f2bf(v);
        }
        return;
    }

    if (blockIdx.x >= NB) {                      // quant role (fold + quantize)
        float A = fold_partials(partial, CAST_BLKS, red, &bc);
        if (blockIdx.x == NB && tid == 0) *amax_store = __float_as_uint(A);
        float s = (A > 0.0f) ? 127.0f / A : 0.0f;
        int i = (blockIdx.x - NB) * 1024 + tid;
        if (i < NQ16) quant16(i, xb, x8, s);
        return;
    }

    int k = blockIdx.x;
    int base  = k * CAP;                         // slack layout, no scan
    int count = gcnt[k];

    for (int i = tid; i < BNODES; i += 1024) hist[i] = 0;
    __syncthreads();

    for (int i = tid; i < count; i += 1024) {
        int w = part[base + i];
        in_buf[i] = w;
        atomicAdd(&hist[w & (BNODES - 1)], 1);
    }
    __syncthreads();
    if (tid < 64) {
        int a = hist[2 * tid], b = hist[2 * tid + 1];
        int s = a + b, incl = s;
        for (int off = 1; off < 64; off <<= 1) {
            int t = __shfl_up(incl, off, 64);
            if (tid >= off) incl += t;
        }
        int excl = incl - s;
        exs[2 * tid] = excl;
        exs[2 * tid + 1] = excl + a;
    }
    __syncthreads();
    if (tid < BNODES) {
        int node = k * BNODES + tid;
        if (node < N_NODES) {
            rbeg[node] = base + exs[tid];
            rend[node] = base + exs[tid] + hist[tid];
        }
        cursor[tid] = exs[tid];
    }
    __syncthreads();
    for (int i = tid; i < count; i += 1024) {
        int w = in_buf[i];
        int r = atomicAdd(&cursor[w & (BNODES - 1)], 1);
        out_buf[r] = w >> BSHIFT;
    }
    __syncthreads();
    for (int i = tid; i < count; i += 1024)
        sorted_src[base + i] = out_buf[i];
}

// ---------------------------------------------------------------------------
// Quantize h (folds HPARTS partials itself; block 0 publishes scales[1]);
// 16 dims/thread, 391 blocks.
// ---------------------------------------------------------------------------
__global__ __launch_bounds__(1024) void quant8f(const unsigned short* __restrict__ inb,
                                                unsigned char* __restrict__ out8,
                                                const float* __restrict__ partial,
                                                unsigned* __restrict__ amax_store) {
    __shared__ float red[16];
    __shared__ float bc;
    float A = fold_partials(partial, HPARTS, red, &bc);
    if (blockIdx.x == 0 && threadIdx.x == 0) *amax_store = __float_as_uint(A);
    float s = (A > 0.0f) ? 127.0f / A : 0.0f;
    int i = blockIdx.x * 1024 + threadIdx.x;
    if (i < NQ16) quant16(i, inb, out8, s);
}

// byte extract: (0,b3,0,b1) from w in one v_perm_b32. aLo keeps bytes 0,2 as
// packed u16 lanes; aHi keeps 1,3.
#define ACCW(w, kk) { aLo[kk] += (w) & 0x00FF00FFu; \
                      aHi[kk] += __builtin_amdgcn_perm(0u, (w), 0x04030401u); }
#define ACC4(v) { ACCW((v).x, 0) ACCW((v).y, 1) ACCW((v).z, 2) ACCW((v).w, 3) }

// ---------------------------------------------------------------------------
// Fused SAGE layer v8 (round-6 structure, best measured 41.6 us — UNCHANGED).
// Locked lessons: shfl gather (not direct loads, r16); sequential 6250-block
// dispatch (not persistent, r17); LDS-staged full-line stores (r13).
// ---------------------------------------------------------------------------
__global__ __launch_bounds__(512, 8) void sage8(
    const int* __restrict__ rbeg, const int* __restrict__ rend,
    const int* __restrict__ nbr,
    const unsigned char* __restrict__ tab8,     // int8 table, 64 B rows
    const unsigned short* __restrict__ selfb,   // bf16 self rows
    const unsigned* __restrict__ amax_bits,     // gather-table absmax
    const unsigned short* __restrict__ wb,      // packed bf16 weights [64][128]
    const float* __restrict__ b_l,
    float* __restrict__ out,                    // fp32 out (layer 2) or null
    unsigned short* __restrict__ outb,          // bf16 out (layer 1) or null
    float* __restrict__ hpart,                  // per-tile |h| partials or null
    int apply_relu)
{
    __shared__ unsigned short a_s[16][136];   // [node][k] bf16 (row 272 B)
    __shared__ float st[16][68];              // staged outputs (padded rows)
    __shared__ float bias[D];
    __shared__ float wred[4];

    int tid = threadIdx.x;
    if (tid < D) bias[tid] = b_l[tid];

    int wave = tid >> 6;          // 0..7
    int lane = tid & 63;
    int nsel = lane >> 5;         // which of the wave's 2 nodes
    int l32  = lane & 31;
    int g    = l32 >> 2;          // neighbor group 0..7
    int c    = l32 & 3;           // 16-byte chunk of the int8 row
    int arow = wave * 2 + nsel;   // 0..15
    int node = blockIdx.x * 16 + arow;   // N_NODES = 6250*16, no tail

    float A  = __uint_as_float(*amax_bits);
    float gs = A * (1.0f / 127.0f);

    int begin = rbeg[node];
    int end   = rend[node];

    // early independent self-row load; nt = don't evict table lines
    uint2v xv = {0, 0};
    if (l32 < 16)
        xv = __builtin_nontemporal_load((const uint2v*)&selfb[(size_t)node * D + 4 * l32]);

    unsigned c16 = (unsigned)(c << 4);
    unsigned aLo[4] = {0, 0, 0, 0};
    unsigned aHi[4] = {0, 0, 0, 0};
    for (int base = begin; base < end; base += 32) {
        int m = end - base; if (m > 32) m = 32;
        int id = (l32 < m) ? __builtin_nontemporal_load(&nbr[base + l32]) : 0;
        int s0 = __shfl(id, nsel * 32 + g,      64);
        int s1 = __shfl(id, nsel * 32 + 8 + g,  64);
        int s2 = __shfl(id, nsel * 32 + 16 + g, 64);
        int s3 = __shfl(id, nsel * 32 + 24 + g, 64);
        bool a0 = (g < m), a1 = (8 + g < m), a2 = (16 + g < m), a3 = (24 + g < m);
        uint4 v0, v1, v2, v3;
        if (a0) v0 = *(const uint4*)(tab8 + ((((unsigned)s0) << 6) | c16));
        if (a1) v1 = *(const uint4*)(tab8 + ((((unsigned)s1) << 6) | c16));
        if (a2) v2 = *(const uint4*)(tab8 + ((((unsigned)s2) << 6) | c16));
        if (a3) v3 = *(const uint4*)(tab8 + ((((unsigned)s3) << 6) | c16));
        if (a0) { ACC4(v0) }
        if (a1) { ACC4(v1) }
        if (a2) { ACC4(v2) }
        if (a3) { ACC4(v3) }
    }

    // reduce across the 8 groups (offsets 4,8,16 -- within the 32-lane half)
#pragma unroll
    for (int off = 4; off <= 16; off <<= 1) {
#pragma unroll
        for (int k = 0; k < 4; ++k) {
            aLo[k] += (unsigned)__shfl_xor((int)aLo[k], off, 64);
            aHi[k] += (unsigned)__shfl_xor((int)aHi[k], off, 64);
        }
    }

    int   deg  = end - begin;
    float invd = 1.0f / fmaxf((float)deg, 1.0f);
    float sc   = gs * invd;
    float nofs = -128.0f * (float)deg * sc;      // fused (-bofs)*sc

    // all-lane dequant: lane (c,g) produces dims 16c+2g, 2g+1 of its node
    {
        unsigned lo01 = (g & 2) ? aLo[1] : aLo[0];
        unsigned lo23 = (g & 2) ? aLo[3] : aLo[2];
        unsigned wLo  = (g & 4) ? lo23 : lo01;
        unsigned hi01 = (g & 2) ? aHi[1] : aHi[0];
        unsigned hi23 = (g & 2) ? aHi[3] : aHi[2];
        unsigned wHi  = (g & 4) ? hi23 : hi01;
        int sh = (g & 1) << 4;
        float d0 = (float)((wLo >> sh) & 0xFFFFu);
        float d1 = (float)((wHi >> sh) & 0xFFFFu);
        float f0 = fmaf(d0, sc, nofs);
        float f1 = fmaf(d1, sc, nofs);
        *(unsigned*)&a_s[arow][16 * c + 2 * g] = cvtpk(f0, f1);
    }
    if (l32 < 16)                   // self row bf16 -> A k=64..127
        *(uint2v*)&a_s[arow][64 + 4 * l32] = xv;
    __syncthreads();                // b1: a_s ready

    if (wave < 4) {
        // ---- MFMA: wave w -> output cols 16w..16w+15 (4 MFMAs) ----
        int quad = lane >> 4;
        int cc   = lane & 15;

        float4v acc = {0.f, 0.f, 0.f, 0.f};
#pragma unroll
        for (int kk = 0; kk < 4; ++kk) {
            short8 af = *(const short8*)&a_s[cc][kk * 32 + quad * 8];
            short8 bf = *(const short8*)(wb + (size_t)(wave * 16 + cc) * 128 + kk * 32 + quad * 8);
            acc = __builtin_amdgcn_mfma_f32_16x16x32_bf16(af, bf, acc, 0, 0, 0);
        }

        int o = wave * 16 + cc;
        float bv = bias[o];
        float vv[4];
#pragma unroll
        for (int r = 0; r < 4; ++r) {
            float v = acc[r] + bv;
            if (apply_relu) v = fmaxf(v, 0.0f);
            vv[r] = v;
            st[quad * 4 + r][o] = v;
        }
        if (hpart) {
            float m = fmaxf(fmaxf(fabsf(vv[0]), fabsf(vv[1])),
                            fmaxf(fabsf(vv[2]), fabsf(vv[3])));
            for (int off = 32; off >= 1; off >>= 1) m = fmaxf(m, __shfl_xor(m, off, 64));
            if (lane == 0) wred[wave] = m;
        }
    }
    __syncthreads();                // b2: st ready

    if (wave >= 4) {                // coalesced full-line stores
        int idx = tid - 256;        // 0..255
        if (outb) {                 // layer 1: bf16, 128 lanes
            if (idx < 128) {
                int row = idx >> 3, c8 = idx & 7;
                const float* p = &st[row][c8 * 8];
                float4v f0 = *(const float4v*)p;
                float4v f1 = *(const float4v*)(p + 4);
                uint4v q;
                q[0] = cvtpk(f0[0], f0[1]); q[1] = cvtpk(f0[2], f0[3]);
                q[2] = cvtpk(f1[0], f1[1]); q[3] = cvtpk(f1[2], f1[3]);
                __builtin_nontemporal_store(q,
                    (uint4v*)&outb[((size_t)(blockIdx.x * 16 + row)) * D + 8 * c8]);
            }
        } else {                    // layer 2: fp32, 256 lanes
            int row = idx >> 4, c4 = idx & 15;
            uint4v q = *(const uint4v*)&st[row][c4 * 4];
            __builtin_nontemporal_store(q,
                (uint4v*)&out[((size_t)(blockIdx.x * 16 + row)) * D + 4 * c4]);
        }
        if (hpart && idx == 0)
            hpart[blockIdx.x] = fmaxf(fmaxf(wred[0], wred[1]), fmaxf(wred[2], wred[3]));
    }
}

// ---------------------------------------------------------------------------
// Launch: 6 dispatches
// ---------------------------------------------------------------------------
extern "C" void kernel_launch(void* const* d_in, const int* in_sizes, int n_in,
                              void* d_out, int out_size, void* d_ws, size_t ws_size,
                              hipStream_t stream) {
    const float* x    = (const float*)d_in[0];
    const int*   ei   = (const int*)d_in[1];   // [2, E]: src = ei, dst = ei + E
    const float* w_l1 = (const float*)d_in[2];
    const float* b_l1 = (const float*)d_in[3];
    const float* w_r1 = (const float*)d_in[4];
    const float* w_l2 = (const float*)d_in[5];
    const float* b_l2 = (const float*)d_in[6];
    const float* w_r2 = (const float*)d_in[7];
    float* out = (float*)d_out;

    const int* src = ei;
    const int* dst = ei + N_EDGES;

    unsigned* scales   = (unsigned*)d_ws;                 // [0]=A_x, [1]=A_h
    int* gcnt          = (int*)d_ws + 4;                  // NB (adjacent: one memset)
    int* rbeg          = gcnt + NB;                       // NPAD
    int* rend          = rbeg + NPAD;                     // NPAD
    int* part          = rend + NPAD;                     // NB*CAP (slack layout)
    int* sorted_src    = part + NB * CAP;                 // NB*CAP (slack layout)
    unsigned short* xb = (unsigned short*)(sorted_src + NB * CAP);  // N*D bf16
    unsigned short* hb = xb + (size_t)N_NODES * D;                  // N*D bf16
    unsigned char* x8  = (unsigned char*)(hb + (size_t)N_NODES * D);// N*D u8
    unsigned char* h8  = x8 + (size_t)N_NODES * D;                  // N*D u8
    unsigned short* wb1 = (unsigned short*)(h8 + (size_t)N_NODES * D); // 64*128
    unsigned short* wb2 = wb1 + D * 2 * D;                             // 64*128
    float* partA       = (float*)(wb2 + D * 2 * D);       // max(CAST_BLKS, HPARTS)

    (void)hipMemsetAsync(d_ws, 0, 16 + NB * sizeof(int), stream);   // scales + gcnt

    front<<<dim3(CAST_BLKS + PB), dim3(1024), 0, stream>>>(x, xb, partA,
                                                           src, dst, gcnt, part);
    back<<<dim3(NB + QBLKS16 + 16), dim3(1024), 0, stream>>>(gcnt, part,
                                                             rbeg, rend, sorted_src,
                                                             xb, x8, partA, &scales[0],
                                                             w_l1, w_r1, wb1,
                                                             w_l2, w_r2, wb2);

    dim3 lblk(512);
    dim3 lgrid(NT);                          // 6250 sequential tiles
    sage8<<<lgrid, lblk, 0, stream>>>(rbeg, rend, sorted_src, x8, xb,
                                      &scales[0], wb1, b_l1,
                                      (float*)nullptr, hb, partA, /*relu=*/1);
    quant8f<<<dim3(QBLKS16), dim3(1024), 0, stream>>>(hb, h8, partA, &scales[1]);
    sage8<<<lgrid, lblk, 0, stream>>>(rbeg, rend, sorted_src, h8, hb,
                                      &scales[1], wb2, b_l2,
                                      out, (unsigned short*)nullptr,
                                      (float*)nullptr, /*relu=*/0);
}